// Round 10
// baseline (144.120 us; speedup 1.0000x reference)
//
#include <hip/hip_runtime.h>
#include <math.h>

#define DIM 128
#define HEADS 8
#define HD 16
#define NPOS 8192      // 32*32*8
#define EPS 1e-5f

// round-to-nearest-even fp32 -> bf16
static __device__ __forceinline__ unsigned short f2bf(float f) {
    unsigned u = __float_as_uint(f);
    return (unsigned short)((u + 0x7fffu + ((u >> 16) & 1u)) >> 16);
}
#define BLO(u) __uint_as_float((u) << 16)
#define BHI(u) __uint_as_float((u) & 0xffff0000u)

// ---------------- instance-norm stats ----------------
__global__ __launch_bounds__(256) void stats_kernel(const float* __restrict__ x,
                                                    const float* __restrict__ skip,
                                                    float* __restrict__ ws) {
    int c = blockIdx.x;
    const float* src; int n; float* mu_out; float* rs_out; int ci;
    if (c < DIM) { ci = c; src = x + c * 1024; n = 1024; mu_out = ws; rs_out = ws + DIM; }
    else { ci = c - DIM; src = skip + (size_t)ci * NPOS; n = NPOS; mu_out = ws + 2*DIM; rs_out = ws + 3*DIM; }
    int t = threadIdx.x;
    float s = 0.f, s2 = 0.f;
    for (int i = t; i < n; i += 256) { float v = src[i]; s += v; s2 = fmaf(v, v, s2); }
    #pragma unroll
    for (int off = 32; off > 0; off >>= 1) {
        s  += __shfl_down(s,  off, 64);
        s2 += __shfl_down(s2, off, 64);
    }
    __shared__ float ls[4], ls2[4];
    int wv = t >> 6;
    if ((t & 63) == 0) { ls[wv] = s; ls2[wv] = s2; }
    __syncthreads();
    if (t == 0) {
        float S  = ls[0] + ls[1] + ls[2] + ls[3];
        float S2 = ls2[0] + ls2[1] + ls2[2] + ls2[3];
        float inv_n = 1.f / (float)n;
        float mu  = S * inv_n;
        float var = S2 * inv_n - mu * mu;
        mu_out[ci] = mu;
        rs_out[ci] = rsqrtf(var + EPS);
    }
}

// ---------------- weight prep: fold instance-norm (and q-scale) into W ----------------
__global__ __launch_bounds__(512) void prep_kernel(const float* __restrict__ Wq, const float* __restrict__ bq,
                                                   const float* __restrict__ Wk, const float* __restrict__ bk,
                                                   const float* __restrict__ Wv, const float* __restrict__ bv,
                                                   const float* __restrict__ ws,
                                                   float* __restrict__ Wp, float* __restrict__ bp) {
    int m = blockIdx.x;
    const float* W = (m == 0) ? Wq : (m == 1) ? Wk : Wv;
    const float* b = (m == 0) ? bq : (m == 1) ? bk : bv;
    const float* mu = (m == 0) ? ws : ws + 2*DIM;
    const float* rs = (m == 0) ? ws + DIM : ws + 3*DIM;
    float scale = (m == 0) ? 0.25f : 1.0f;

    int t = threadIdx.x;
    int j = blockIdx.y * 32 + (t & 31);
    int g = t >> 5;
    float acc = 0.f;
    for (int ci = g * 8; ci < g * 8 + 8; ++ci) {
        float w  = W[ci * 128 + j];
        float wp = rs[ci] * w * scale;
        Wp[m * 16384 + ci * 128 + j] = wp;
        acc = fmaf(mu[ci], wp, acc);
    }
    __shared__ float red[512];
    red[t] = acc;
    __syncthreads();
    if (g == 0) {
        float ssum = 0.f;
        #pragma unroll
        for (int r = 0; r < 16; ++r) ssum += red[r * 32 + (t & 31)];
        bp[m * 128 + j] = scale * b[j] - ssum;
    }
}

// ---------------- q/k/v projections: 4pos x 4ch per thread, A transposed in LDS ----------------
__global__ __launch_bounds__(256) void qkv_kernel(const float* __restrict__ x,
                                                  const float* __restrict__ skip,
                                                  const float* __restrict__ Wp,
                                                  const float* __restrict__ bp,
                                                  float* __restrict__ q_out,
                                                  float* __restrict__ k_out,
                                                  float* __restrict__ v_out) {
    __shared__ float at[128 * 68];     // A_t[ci][pos], row stride 68
    __shared__ float wl[128 * 64];     // W'[ci][half-local ch]
    int t = threadIdx.x;
    int which = blockIdx.y;
    int half  = blockIdx.z;
    int n0 = blockIdx.x * 64;

    {
        const float4* W4 = (const float4*)(Wp + which * 16384);
        float4* wl4 = (float4*)wl;
        for (int i4 = t; i4 < 2048; i4 += 256) {
            int ci = i4 >> 4, j4 = i4 & 15;
            wl4[ci * 16 + j4] = W4[ci * 32 + half * 16 + j4];
        }
    }
    if (which == 0) {
        for (int i4 = t; i4 < 2048; i4 += 256) {
            int ci = i4 >> 4, ln4 = (i4 & 15) * 4;
            int n = n0 + ln4;
            int hc = n >> 8, wc = (n >> 3) & 31, zc = n & 7;
            float2 f = *(const float2*)(x + ci * 1024 + (hc >> 1) * 64 + (wc >> 1) * 4 + (zc >> 1));
            *(float4*)(at + ci * 68 + ln4) = make_float4(f.x, f.x, f.y, f.y);
        }
    } else {
        for (int i4 = t; i4 < 2048; i4 += 256) {
            int ci = i4 >> 4, ln4 = (i4 & 15) * 4;
            float4 f = *(const float4*)(skip + (size_t)ci * NPOS + n0 + ln4);
            *(float4*)(at + ci * 68 + ln4) = f;
        }
    }
    __syncthreads();

    int pg = t & 15, cg = t >> 4;
    const float* bb = bp + which * 128 + half * 64 + cg * 4;
    float4 bv4 = *(const float4*)bb;
    float4 acc[4];
    #pragma unroll
    for (int ps = 0; ps < 4; ++ps) acc[ps] = bv4;

    const float* ap = at + pg * 4;
    const float* wp = wl + cg * 4;
    #pragma unroll 4
    for (int ci = 0; ci < 128; ++ci) {
        float4 a4 = *(const float4*)(ap + ci * 68);
        float4 w4 = *(const float4*)(wp + ci * 64);
        float av[4] = { a4.x, a4.y, a4.z, a4.w };
        #pragma unroll
        for (int ps = 0; ps < 4; ++ps) {
            float a = av[ps];
            acc[ps].x = fmaf(a, w4.x, acc[ps].x);
            acc[ps].y = fmaf(a, w4.y, acc[ps].y);
            acc[ps].z = fmaf(a, w4.z, acc[ps].z);
            acc[ps].w = fmaf(a, w4.w, acc[ps].w);
        }
    }
    float* outp = (which == 0) ? q_out : (which == 1) ? k_out : v_out;
    int p0 = n0 + pg * 4;
    #pragma unroll
    for (int ps = 0; ps < 4; ++ps)
        *(float4*)(outp + (size_t)(p0 + ps) * 128 + half * 64 + cg * 4) = acc[ps];
}

// ---------------- neighborhood attention: conflict-resistant LDS, bf16 k AND v ----------------
// Block = (4x4x8 tile, head); halo 8x8x8 = 512.
// Slot base(nh,nw,nz) = nh*64 + nz*8 + ((nw+nz)&7) -> 16B-channel (nw+nz)&7.
// k,v bf16: chunk c2 (dims 8*c2..+7) at (c2*520+base)*8 ushorts.
// LDS 36.2 KB. Per 64-visit wave-iter: 2 b128 (k) + 2 b128 (v) + 1 b32 (bias)
// = ~54 LDS cyc (vs 78 with fp32 k) -> LDS-issue bound attn drops ~30%.
__global__ __launch_bounds__(512) void attn_kernel(const float* __restrict__ q,
                                                   const float* __restrict__ k,
                                                   const float* __restrict__ v,
                                                   const float* __restrict__ rpb,
                                                   float* __restrict__ ao_t) {
    __shared__ __align__(16) unsigned short kbf[2 * 520 * 8]; // 16640 B
    __shared__ __align__(16) unsigned short vbf[2 * 520 * 8]; // 16640 B
    __shared__ float bias_l[729];                             // 2916 B

    int blk = blockIdx.x;
    int h    = blk & 7;
    int tile = blk >> 3;
    int h0 = (tile >> 3) * 4;
    int w0 = (tile & 7) * 4;
    int bh0 = min(max(h0 - 2, 0), 24);
    int bw0 = min(max(w0 - 2, 0), 24);
    int t = threadIdx.x;

    // ---- stage k AND v halo as bf16 ----
    for (int idx = t; idx < 1024; idx += 512) {
        int nbr = idx >> 1, c2 = idx & 1;
        int nh = nbr >> 6, nw = (nbr >> 3) & 7, nz = nbr & 7;
        int n = (bh0 + nh) * 256 + (bw0 + nw) * 8 + nz;
        int base = nh * 64 + nz * 8 + ((nw + nz) & 7);
        const float* kp = k + (size_t)n * 128 + h * 16 + c2 * 8;
        const float* vp = v + (size_t)n * 128 + h * 16 + c2 * 8;
        float4 ka = *(const float4*)kp;
        float4 kb = *(const float4*)(kp + 4);
        float4 va = *(const float4*)vp;
        float4 vb = *(const float4*)(vp + 4);
        uint4 pk, pv;
        pk.x = ((unsigned)f2bf(ka.y) << 16) | f2bf(ka.x);
        pk.y = ((unsigned)f2bf(ka.w) << 16) | f2bf(ka.z);
        pk.z = ((unsigned)f2bf(kb.y) << 16) | f2bf(kb.x);
        pk.w = ((unsigned)f2bf(kb.w) << 16) | f2bf(kb.z);
        pv.x = ((unsigned)f2bf(va.y) << 16) | f2bf(va.x);
        pv.y = ((unsigned)f2bf(va.w) << 16) | f2bf(va.z);
        pv.z = ((unsigned)f2bf(vb.y) << 16) | f2bf(vb.x);
        pv.w = ((unsigned)f2bf(vb.w) << 16) | f2bf(vb.z);
        *(uint4*)(kbf + (c2 * 520 + base) * 8) = pk;
        *(uint4*)(vbf + (c2 * 520 + base) * 8) = pv;
    }
    for (int idx = t; idx < 729; idx += 512) bias_l[idx] = rpb[h * 729 + idx];
    __syncthreads();

    int s = t & 3, p = t >> 2;
    int ph = p >> 5, pw = (p >> 3) & 3, pz = p & 7;
    int hc = h0 + ph, wc = w0 + pw, zc = pz;
    int sh = min(max(hc - 2, 0), 27);
    int sw = min(max(wc - 2, 0), 27);
    int sz = min(max(zc - 2, 0), 3);
    int hb = sh - bh0, wb = sw - bw0;
    int bias_base = (sh - hc + 4) * 81 + (sw - wc + 4) * 9 + (sz - zc + 4);
    int n = hc * 256 + wc * 8 + zc;

    float qv[16];
    #pragma unroll
    for (int i = 0; i < 4; ++i)
        ((float4*)qv)[i] = *(const float4*)(q + (size_t)n * 128 + h * 16 + i * 4);

    float o[16];
    #pragma unroll
    for (int d = 0; d < 16; ++d) o[d] = 0.f;
    float l = 0.f;

    int cnt   = s ? 31 : 32;
    int start = s * 31 + (s ? 1 : 0);
    int i0 = p & 31; if (i0 >= cnt) i0 -= cnt;

    for (int it = 0; it < cnt; ++it) {
        int ii = i0 + it; if (ii >= cnt) ii -= cnt;
        int j = start + ii;
        int jh = (j * 41) >> 10;
        int jr = j - jh * 25;
        int jw = (jr * 13) >> 6;
        int jz = jr - jw * 5;
        int nz = sz + jz;
        int base = (hb + jh) * 64 + nz * 8 + ((wb + jw + nz) & 7);
        float bias = bias_l[bias_base + jh * 81 + jw * 9 + jz];

        uint4 ka = *(const uint4*)(kbf + base * 8);
        uint4 kb = *(const uint4*)(kbf + (520 + base) * 8);
        float d0 = 0.f, d1 = 0.f, d2 = 0.f, d3 = 0.f;
        d0 = fmaf(BLO(ka.x), qv[0],  d0);
        d0 = fmaf(BHI(ka.x), qv[1],  d0);
        d0 = fmaf(BLO(ka.y), qv[2],  d0);
        d0 = fmaf(BHI(ka.y), qv[3],  d0);
        d1 = fmaf(BLO(ka.z), qv[4],  d1);
        d1 = fmaf(BHI(ka.z), qv[5],  d1);
        d1 = fmaf(BLO(ka.w), qv[6],  d1);
        d1 = fmaf(BHI(ka.w), qv[7],  d1);
        d2 = fmaf(BLO(kb.x), qv[8],  d2);
        d2 = fmaf(BHI(kb.x), qv[9],  d2);
        d2 = fmaf(BLO(kb.y), qv[10], d2);
        d2 = fmaf(BHI(kb.y), qv[11], d2);
        d3 = fmaf(BLO(kb.z), qv[12], d3);
        d3 = fmaf(BHI(kb.z), qv[13], d3);
        d3 = fmaf(BLO(kb.w), qv[14], d3);
        d3 = fmaf(BHI(kb.w), qv[15], d3);
        float sc = (d0 + d1) + (d2 + d3) + bias;
        float pp = __expf(sc);
        l += pp;

        uint4 va = *(const uint4*)(vbf + base * 8);
        uint4 vb = *(const uint4*)(vbf + (520 + base) * 8);
        o[0]  = fmaf(pp, BLO(va.x), o[0]);
        o[1]  = fmaf(pp, BHI(va.x), o[1]);
        o[2]  = fmaf(pp, BLO(va.y), o[2]);
        o[3]  = fmaf(pp, BHI(va.y), o[3]);
        o[4]  = fmaf(pp, BLO(va.z), o[4]);
        o[5]  = fmaf(pp, BHI(va.z), o[5]);
        o[6]  = fmaf(pp, BLO(va.w), o[6]);
        o[7]  = fmaf(pp, BHI(va.w), o[7]);
        o[8]  = fmaf(pp, BLO(vb.x), o[8]);
        o[9]  = fmaf(pp, BHI(vb.x), o[9]);
        o[10] = fmaf(pp, BLO(vb.y), o[10]);
        o[11] = fmaf(pp, BHI(vb.y), o[11]);
        o[12] = fmaf(pp, BLO(vb.z), o[12]);
        o[13] = fmaf(pp, BHI(vb.z), o[13]);
        o[14] = fmaf(pp, BLO(vb.w), o[14]);
        o[15] = fmaf(pp, BHI(vb.w), o[15]);
    }

    #pragma unroll
    for (int step = 1; step <= 2; step <<= 1) {
        l += __shfl_xor(l, step, 64);
        #pragma unroll
        for (int d = 0; d < 16; ++d) o[d] += __shfl_xor(o[d], step, 64);
    }
    float inv = 1.f / l;
    #pragma unroll
    for (int j = 0; j < 4; ++j)
        ao_t[(size_t)(h * 16 + s * 4 + j) * NPOS + n] = o[4 * s + j] * inv;
}

// ---------------- output projection: same 4pos x 4ch structure as qkv ----------------
__global__ __launch_bounds__(256) void proj_kernel(const float* __restrict__ ao_t,
                                                   const float* __restrict__ Wo,
                                                   const float* __restrict__ bo,
                                                   float* __restrict__ out) {
    __shared__ float at[128 * 68];
    __shared__ float wl[128 * 64];
    int t = threadIdx.x;
    int half = blockIdx.y;
    int n0 = blockIdx.x * 64;

    {
        const float4* W4 = (const float4*)Wo;
        float4* wl4 = (float4*)wl;
        for (int i4 = t; i4 < 2048; i4 += 256) {
            int ci = i4 >> 4, j4 = i4 & 15;
            wl4[ci * 16 + j4] = W4[ci * 32 + half * 16 + j4];
        }
    }
    for (int i4 = t; i4 < 2048; i4 += 256) {
        int ci = i4 >> 4, ln4 = (i4 & 15) * 4;
        float4 f = *(const float4*)(ao_t + (size_t)ci * NPOS + n0 + ln4);
        *(float4*)(at + ci * 68 + ln4) = f;
    }
    __syncthreads();

    int pg = t & 15, cg = t >> 4;
    float4 bv4 = *(const float4*)(bo + half * 64 + cg * 4);
    float4 acc[4];
    #pragma unroll
    for (int ps = 0; ps < 4; ++ps) acc[ps] = bv4;

    const float* ap = at + pg * 4;
    const float* wp = wl + cg * 4;
    #pragma unroll 4
    for (int ci = 0; ci < 128; ++ci) {
        float4 a4 = *(const float4*)(ap + ci * 68);
        float4 w4 = *(const float4*)(wp + ci * 64);
        float av[4] = { a4.x, a4.y, a4.z, a4.w };
        #pragma unroll
        for (int ps = 0; ps < 4; ++ps) {
            float a = av[ps];
            acc[ps].x = fmaf(a, w4.x, acc[ps].x);
            acc[ps].y = fmaf(a, w4.y, acc[ps].y);
            acc[ps].z = fmaf(a, w4.z, acc[ps].z);
            acc[ps].w = fmaf(a, w4.w, acc[ps].w);
        }
    }
    int p0 = n0 + pg * 4;
    int jbase = half * 64 + cg * 4;
    *(float4*)(out + (size_t)(jbase + 0) * NPOS + p0) = make_float4(acc[0].x, acc[1].x, acc[2].x, acc[3].x);
    *(float4*)(out + (size_t)(jbase + 1) * NPOS + p0) = make_float4(acc[0].y, acc[1].y, acc[2].y, acc[3].y);
    *(float4*)(out + (size_t)(jbase + 2) * NPOS + p0) = make_float4(acc[0].z, acc[1].z, acc[2].z, acc[3].z);
    *(float4*)(out + (size_t)(jbase + 3) * NPOS + p0) = make_float4(acc[0].w, acc[1].w, acc[2].w, acc[3].w);
}

extern "C" void kernel_launch(void* const* d_in, const int* in_sizes, int n_in,
                              void* d_out, int out_size, void* d_ws, size_t ws_size,
                              hipStream_t stream) {
    const float* x    = (const float*)d_in[0];
    const float* skip = (const float*)d_in[1];
    const float* Wq   = (const float*)d_in[2];
    const float* bq   = (const float*)d_in[3];
    const float* Wk   = (const float*)d_in[4];
    const float* bk   = (const float*)d_in[5];
    const float* Wv   = (const float*)d_in[6];
    const float* bv   = (const float*)d_in[7];
    const float* rpb  = (const float*)d_in[8];
    const float* Wo   = (const float*)d_in[9];
    const float* bo   = (const float*)d_in[10];
    float* out = (float*)d_out;

    float* ws   = (float*)d_ws;
    float* q    = ws  + 512;
    float* k    = q   + (size_t)NPOS * 128;
    float* v    = k   + (size_t)NPOS * 128;
    float* ao_t = v   + (size_t)NPOS * 128;
    float* Wp   = ao_t + (size_t)NPOS * 128;
    float* bp   = Wp  + 3 * 16384;

    stats_kernel<<<256, 256, 0, stream>>>(x, skip, ws);
    prep_kernel<<<dim3(3, 4), 512, 0, stream>>>(Wq, bq, Wk, bk, Wv, bv, ws, Wp, bp);
    qkv_kernel<<<dim3(128, 3, 2), 256, 0, stream>>>(x, skip, Wp, bp, q, k, v);
    attn_kernel<<<512, 512, 0, stream>>>(q, k, v, rpb, ao_t);
    proj_kernel<<<dim3(128, 2), 256, 0, stream>>>(ao_t, Wo, bo, out);
}

// Round 11
// 142.446 us; speedup vs baseline: 1.0118x; 1.0118x over previous
//
#include <hip/hip_runtime.h>
#include <math.h>

#define DIM 128
#define HEADS 8
#define HD 16
#define NPOS 8192      // 32*32*8
#define EPS 1e-5f

// round-to-nearest-even fp32 -> bf16
static __device__ __forceinline__ unsigned short f2bf(float f) {
    unsigned u = __float_as_uint(f);
    return (unsigned short)((u + 0x7fffu + ((u >> 16) & 1u)) >> 16);
}
#define BLO(u) __uint_as_float((u) << 16)
#define BHI(u) __uint_as_float((u) & 0xffff0000u)

// ---------------- instance-norm stats ----------------
// ws: [0,128) mu_x [128,256) rs_x [256,384) mu_s [384,512) rs_s
__global__ __launch_bounds__(256) void stats_kernel(const float* __restrict__ x,
                                                    const float* __restrict__ skip,
                                                    float* __restrict__ ws) {
    int c = blockIdx.x;
    const float* src; int n; float* mu_out; float* rs_out; int ci;
    if (c < DIM) { ci = c; src = x + c * 1024; n = 1024; mu_out = ws; rs_out = ws + DIM; }
    else { ci = c - DIM; src = skip + (size_t)ci * NPOS; n = NPOS; mu_out = ws + 2*DIM; rs_out = ws + 3*DIM; }
    int t = threadIdx.x;
    float s = 0.f, s2 = 0.f;
    for (int i = t; i < n; i += 256) { float v = src[i]; s += v; s2 = fmaf(v, v, s2); }
    #pragma unroll
    for (int off = 32; off > 0; off >>= 1) {
        s  += __shfl_down(s,  off, 64);
        s2 += __shfl_down(s2, off, 64);
    }
    __shared__ float ls[4], ls2[4];
    int wv = t >> 6;
    if ((t & 63) == 0) { ls[wv] = s; ls2[wv] = s2; }
    __syncthreads();
    if (t == 0) {
        float S  = ls[0] + ls[1] + ls[2] + ls[3];
        float S2 = ls2[0] + ls2[1] + ls2[2] + ls2[3];
        float inv_n = 1.f / (float)n;
        float mu  = S * inv_n;
        float var = S2 * inv_n - mu * mu;
        mu_out[ci] = mu;
        rs_out[ci] = rsqrtf(var + EPS);
    }
}

// ---------------- q/k/v projections: norm folded into A-staging, k/v packed bf16 out ----------------
// grid (128, 3, 2): 64-pos tile x {q,k,v} x ch-half; 256 threads.
// Thread (pg=t&15, cg=t>>4): 4 pos x 4 ch. Per ci: 2 ds_read_b128 + 16 FMA.
__global__ __launch_bounds__(256) void qkv_kernel(const float* __restrict__ x,
                                                  const float* __restrict__ skip,
                                                  const float* __restrict__ Wq, const float* __restrict__ bq,
                                                  const float* __restrict__ Wk, const float* __restrict__ bk,
                                                  const float* __restrict__ Wv, const float* __restrict__ bv,
                                                  const float* __restrict__ ws,
                                                  float* __restrict__ q_out,
                                                  unsigned* __restrict__ k_out,
                                                  unsigned* __restrict__ v_out) {
    __shared__ float at[128 * 68];     // normalized A_t[ci][pos], row stride 68
    __shared__ float wl[128 * 64];     // raw W[ci][half-local ch]
    int t = threadIdx.x;
    int which = blockIdx.y;
    int half  = blockIdx.z;
    int n0 = blockIdx.x * 64;

    const float* W = (which == 0) ? Wq : (which == 1) ? Wk : Wv;
    const float* b = (which == 0) ? bq : (which == 1) ? bk : bv;
    {
        const float4* W4 = (const float4*)W;
        float4* wl4 = (float4*)wl;
        for (int i4 = t; i4 < 2048; i4 += 256) {
            int ci = i4 >> 4, j4 = i4 & 15;
            wl4[ci * 16 + j4] = W4[ci * 32 + half * 16 + j4];
        }
    }
    const float* mu = (which == 0) ? ws : ws + 2*DIM;
    const float* rs = (which == 0) ? ws + DIM : ws + 3*DIM;
    if (which == 0) {
        for (int i4 = t; i4 < 2048; i4 += 256) {
            int ci = i4 >> 4, ln4 = (i4 & 15) * 4;
            int n = n0 + ln4;
            int hc = n >> 8, wc = (n >> 3) & 31, zc = n & 7;
            float2 f = *(const float2*)(x + ci * 1024 + (hc >> 1) * 64 + (wc >> 1) * 4 + (zc >> 1));
            float m_ = mu[ci], r_ = rs[ci];
            float a0 = (f.x - m_) * r_, a1 = (f.y - m_) * r_;
            *(float4*)(at + ci * 68 + ln4) = make_float4(a0, a0, a1, a1);
        }
    } else {
        for (int i4 = t; i4 < 2048; i4 += 256) {
            int ci = i4 >> 4, ln4 = (i4 & 15) * 4;
            float4 f = *(const float4*)(skip + (size_t)ci * NPOS + n0 + ln4);
            float m_ = mu[ci], r_ = rs[ci];
            *(float4*)(at + ci * 68 + ln4) =
                make_float4((f.x - m_) * r_, (f.y - m_) * r_, (f.z - m_) * r_, (f.w - m_) * r_);
        }
    }
    __syncthreads();

    int pg = t & 15, cg = t >> 4;
    float4 bv4 = *(const float4*)(b + half * 64 + cg * 4);
    float4 acc[4];
    #pragma unroll
    for (int ps = 0; ps < 4; ++ps) acc[ps] = bv4;

    const float* ap = at + pg * 4;
    const float* wp = wl + cg * 4;
    #pragma unroll 4
    for (int ci = 0; ci < 128; ++ci) {
        float4 a4 = *(const float4*)(ap + ci * 68);
        float4 w4 = *(const float4*)(wp + ci * 64);
        float av[4] = { a4.x, a4.y, a4.z, a4.w };
        #pragma unroll
        for (int ps = 0; ps < 4; ++ps) {
            float a = av[ps];
            acc[ps].x = fmaf(a, w4.x, acc[ps].x);
            acc[ps].y = fmaf(a, w4.y, acc[ps].y);
            acc[ps].z = fmaf(a, w4.z, acc[ps].z);
            acc[ps].w = fmaf(a, w4.w, acc[ps].w);
        }
    }
    int p0 = n0 + pg * 4;
    if (which == 0) {
        #pragma unroll
        for (int ps = 0; ps < 4; ++ps) {
            float4 r = make_float4(acc[ps].x * 0.25f, acc[ps].y * 0.25f,
                                   acc[ps].z * 0.25f, acc[ps].w * 0.25f);
            *(float4*)(q_out + (size_t)(p0 + ps) * 128 + half * 64 + cg * 4) = r;
        }
    } else {
        unsigned* outp = (which == 1) ? k_out : v_out;
        #pragma unroll
        for (int ps = 0; ps < 4; ++ps) {
            uint2 pk;
            pk.x = ((unsigned)f2bf(acc[ps].y) << 16) | f2bf(acc[ps].x);
            pk.y = ((unsigned)f2bf(acc[ps].w) << 16) | f2bf(acc[ps].z);
            *(uint2*)(outp + (size_t)(p0 + ps) * 64 + half * 32 + cg * 2) = pk;
        }
    }
}

// ---------------- neighborhood attention: half-tile, 8 slots, packed bf16 k/v ----------------
// grid 1024 = (64 tiles x 2 w-halves) x 8 heads; 512 thr. Block covers 4x2x8 = 64
// positions; halo 8x6x8 = 384. LDS slot (16B): base = nh*52 + nw*8 + ((nz+nw)&7)
// -> channel mixes z and w. LDS ~29.5 KB; __launch_bounds__(512,6) -> >=24 waves/CU
// (latency-hiding test vs R10's 16). Staging = direct uint4 copy (no cvt).
__global__ __launch_bounds__(512, 6) void attn_kernel(const float* __restrict__ q,
                                                      const unsigned* __restrict__ kb,
                                                      const unsigned* __restrict__ vb,
                                                      const float* __restrict__ rpb,
                                                      float* __restrict__ ao_t) {
    __shared__ uint4 kbf[2 * 416];   // 13312 B
    __shared__ uint4 vbf[2 * 416];   // 13312 B
    __shared__ float bias_l[729];    // 2916 B

    int blk = blockIdx.x;
    int h     = blk & 7;
    int rest  = blk >> 3;            // 0..127
    int halfw = rest & 1;
    int tile  = rest >> 1;           // 0..63
    int h0 = (tile >> 3) * 4;
    int w0 = (tile & 7) * 4 + halfw * 2;
    int bh0 = min(max(h0 - 2, 0), 24);
    int bw0 = min(max(w0 - 2, 0), 26);
    int t = threadIdx.x;

    // ---- stage k/v halo: 384 nbrs x 2 chunk-halves, direct 16B copies ----
    for (int idx = t; idx < 768; idx += 512) {
        int c2 = idx & 1;
        int r  = idx >> 1;
        int nz = r & 7;
        int q2 = r >> 3;                 // 0..47
        int nh = (q2 * 43) >> 8;         // q2 / 6
        int nw = q2 - nh * 6;
        int n = (bh0 + nh) * 256 + (bw0 + nw) * 8 + nz;
        int base = nh * 52 + nw * 8 + ((nz + nw) & 7);
        kbf[c2 * 416 + base] = *(const uint4*)(kb + (size_t)n * 64 + h * 8 + c2 * 4);
        vbf[c2 * 416 + base] = *(const uint4*)(vb + (size_t)n * 64 + h * 8 + c2 * 4);
    }
    for (int idx = t; idx < 729; idx += 512) bias_l[idx] = rpb[h * 729 + idx];
    __syncthreads();

    int s = t & 7, p = t >> 3;           // 8 slots x 64 positions
    int ph = p >> 4, pw = (p >> 3) & 1, pz = p & 7;
    int hc = h0 + ph, wc = w0 + pw, zc = pz;
    int sh = min(max(hc - 2, 0), 27);
    int sw = min(max(wc - 2, 0), 27);
    int sz = min(max(zc - 2, 0), 3);
    int hb = sh - bh0, wb = sw - bw0;
    int bias_base = (sh - hc + 4) * 81 + (sw - wc + 4) * 9 + (sz - zc + 4);
    int n = hc * 256 + wc * 8 + zc;

    float qv[16];
    #pragma unroll
    for (int i = 0; i < 4; ++i)
        ((float4*)qv)[i] = *(const float4*)(q + (size_t)n * 128 + h * 16 + i * 4);

    float o[16];
    #pragma unroll
    for (int d = 0; d < 16; ++d) o[d] = 0.f;
    float l = 0.f;

    // slot partition: s<5 -> 16 nbrs, s>=5 -> 15 (total 125)
    int cnt   = (s < 5) ? 16 : 15;
    int start = (s < 5) ? 16 * s : 15 * s + 5;
    int i0 = p & 15; if (i0 >= cnt) i0 -= cnt;

    for (int it = 0; it < cnt; ++it) {
        int ii = i0 + it; if (ii >= cnt) ii -= cnt;
        int j = start + ii;
        int jh = (j * 41) >> 10;         // j / 25
        int jr = j - jh * 25;
        int jw = (jr * 13) >> 6;         // jr / 5
        int jz = jr - jw * 5;
        int nnw = wb + jw;
        int nnz = sz + jz;
        int base = (hb + jh) * 52 + nnw * 8 + ((nnz + nnw) & 7);
        float bias = bias_l[bias_base + jh * 81 + jw * 9 + jz];

        uint4 ka = kbf[base];
        uint4 k2 = kbf[416 + base];
        float d0 = 0.f, d1 = 0.f, d2 = 0.f, d3 = 0.f;
        d0 = fmaf(BLO(ka.x), qv[0],  d0);
        d0 = fmaf(BHI(ka.x), qv[1],  d0);
        d0 = fmaf(BLO(ka.y), qv[2],  d0);
        d0 = fmaf(BHI(ka.y), qv[3],  d0);
        d1 = fmaf(BLO(ka.z), qv[4],  d1);
        d1 = fmaf(BHI(ka.z), qv[5],  d1);
        d1 = fmaf(BLO(ka.w), qv[6],  d1);
        d1 = fmaf(BHI(ka.w), qv[7],  d1);
        d2 = fmaf(BLO(k2.x), qv[8],  d2);
        d2 = fmaf(BHI(k2.x), qv[9],  d2);
        d2 = fmaf(BLO(k2.y), qv[10], d2);
        d2 = fmaf(BHI(k2.y), qv[11], d2);
        d3 = fmaf(BLO(k2.z), qv[12], d3);
        d3 = fmaf(BHI(k2.z), qv[13], d3);
        d3 = fmaf(BLO(k2.w), qv[14], d3);
        d3 = fmaf(BHI(k2.w), qv[15], d3);
        float sc = (d0 + d1) + (d2 + d3) + bias;
        float pp = __expf(sc);
        l += pp;

        uint4 va = vbf[base];
        uint4 v2 = vbf[416 + base];
        o[0]  = fmaf(pp, BLO(va.x), o[0]);
        o[1]  = fmaf(pp, BHI(va.x), o[1]);
        o[2]  = fmaf(pp, BLO(va.y), o[2]);
        o[3]  = fmaf(pp, BHI(va.y), o[3]);
        o[4]  = fmaf(pp, BLO(va.z), o[4]);
        o[5]  = fmaf(pp, BHI(va.z), o[5]);
        o[6]  = fmaf(pp, BLO(va.w), o[6]);
        o[7]  = fmaf(pp, BHI(va.w), o[7]);
        o[8]  = fmaf(pp, BLO(v2.x), o[8]);
        o[9]  = fmaf(pp, BHI(v2.x), o[9]);
        o[10] = fmaf(pp, BLO(v2.y), o[10]);
        o[11] = fmaf(pp, BHI(v2.y), o[11]);
        o[12] = fmaf(pp, BLO(v2.z), o[12]);
        o[13] = fmaf(pp, BHI(v2.z), o[13]);
        o[14] = fmaf(pp, BLO(v2.w), o[14]);
        o[15] = fmaf(pp, BHI(v2.w), o[15]);
    }

    // merge 8 slots (adjacent lanes)
    #pragma unroll
    for (int step = 1; step <= 4; step <<= 1) {
        l += __shfl_xor(l, step, 64);
        #pragma unroll
        for (int d = 0; d < 16; ++d) o[d] += __shfl_xor(o[d], step, 64);
    }
    float inv = 1.f / l;
    // lane s stores dims 2s, 2s+1 (transposed [c][n])
    ao_t[(size_t)(h * 16 + 2 * s)     * NPOS + n] = o[2 * s]     * inv;
    ao_t[(size_t)(h * 16 + 2 * s + 1) * NPOS + n] = o[2 * s + 1] * inv;
}

// ---------------- output projection: 4pos x 4ch, A (ao_t) transposed in LDS ----------------
__global__ __launch_bounds__(256) void proj_kernel(const float* __restrict__ ao_t,
                                                   const float* __restrict__ Wo,
                                                   const float* __restrict__ bo,
                                                   float* __restrict__ out) {
    __shared__ float at[128 * 68];
    __shared__ float wl[128 * 64];
    int t = threadIdx.x;
    int half = blockIdx.y;
    int n0 = blockIdx.x * 64;

    {
        const float4* W4 = (const float4*)Wo;
        float4* wl4 = (float4*)wl;
        for (int i4 = t; i4 < 2048; i4 += 256) {
            int ci = i4 >> 4, j4 = i4 & 15;
            wl4[ci * 16 + j4] = W4[ci * 32 + half * 16 + j4];
        }
    }
    for (int i4 = t; i4 < 2048; i4 += 256) {
        int ci = i4 >> 4, ln4 = (i4 & 15) * 4;
        float4 f = *(const float4*)(ao_t + (size_t)ci * NPOS + n0 + ln4);
        *(float4*)(at + ci * 68 + ln4) = f;
    }
    __syncthreads();

    int pg = t & 15, cg = t >> 4;
    float4 bv4 = *(const float4*)(bo + half * 64 + cg * 4);
    float4 acc[4];
    #pragma unroll
    for (int ps = 0; ps < 4; ++ps) acc[ps] = bv4;

    const float* ap = at + pg * 4;
    const float* wp = wl + cg * 4;
    #pragma unroll 4
    for (int ci = 0; ci < 128; ++ci) {
        float4 a4 = *(const float4*)(ap + ci * 68);
        float4 w4 = *(const float4*)(wp + ci * 64);
        float av[4] = { a4.x, a4.y, a4.z, a4.w };
        #pragma unroll
        for (int ps = 0; ps < 4; ++ps) {
            float a = av[ps];
            acc[ps].x = fmaf(a, w4.x, acc[ps].x);
            acc[ps].y = fmaf(a, w4.y, acc[ps].y);
            acc[ps].z = fmaf(a, w4.z, acc[ps].z);
            acc[ps].w = fmaf(a, w4.w, acc[ps].w);
        }
    }
    int p0 = n0 + pg * 4;
    int jbase = half * 64 + cg * 4;
    *(float4*)(out + (size_t)(jbase + 0) * NPOS + p0) = make_float4(acc[0].x, acc[1].x, acc[2].x, acc[3].x);
    *(float4*)(out + (size_t)(jbase + 1) * NPOS + p0) = make_float4(acc[0].y, acc[1].y, acc[2].y, acc[3].y);
    *(float4*)(out + (size_t)(jbase + 2) * NPOS + p0) = make_float4(acc[0].z, acc[1].z, acc[2].z, acc[3].z);
    *(float4*)(out + (size_t)(jbase + 3) * NPOS + p0) = make_float4(acc[0].w, acc[1].w, acc[2].w, acc[3].w);
}

extern "C" void kernel_launch(void* const* d_in, const int* in_sizes, int n_in,
                              void* d_out, int out_size, void* d_ws, size_t ws_size,
                              hipStream_t stream) {
    const float* x    = (const float*)d_in[0];
    const float* skip = (const float*)d_in[1];
    const float* Wq   = (const float*)d_in[2];
    const float* bq   = (const float*)d_in[3];
    const float* Wk   = (const float*)d_in[4];
    const float* bk   = (const float*)d_in[5];
    const float* Wv   = (const float*)d_in[6];
    const float* bv   = (const float*)d_in[7];
    const float* rpb  = (const float*)d_in[8];
    const float* Wo   = (const float*)d_in[9];
    const float* bo   = (const float*)d_in[10];
    float* out = (float*)d_out;

    float*    ws   = (float*)d_ws;
    float*    q    = ws + 512;                       // 8192*128 fp32
    unsigned* kbp  = (unsigned*)(q + (size_t)NPOS * 128);   // 8192*64 packed bf16
    unsigned* vbp  = kbp + (size_t)NPOS * 64;
    float*    ao_t = (float*)(vbp + (size_t)NPOS * 64);     // 8192*128 fp32

    stats_kernel<<<256, 256, 0, stream>>>(x, skip, ws);
    qkv_kernel<<<dim3(128, 3, 2), 256, 0, stream>>>(x, skip, Wq, bq, Wk, bk, Wv, bv, ws, q, kbp, vbp);
    attn_kernel<<<1024, 512, 0, stream>>>(q, kbp, vbp, rpb, ao_t);
    proj_kernel<<<dim3(128, 2), 256, 0, stream>>>(ao_t, Wo, bo, out);
}